// Round 1
// baseline (1722.286 us; speedup 1.0000x reference)
//
#include <hip/hip_runtime.h>
#include <cstddef>
#include <cstdint>

#define NB 8
#define NPTS 4096
#define NS 1024
#define NK 32
#define ND 64

// ------------------------------------------------------------------
// FPS: one block per batch, 1024 threads, 4 points/thread in registers.
// Packed key (distbits<<32 | ~idx) -> max == argmax with first-occurrence
// tie-break, matching jnp.argmax. One barrier/iter (parity LDS buffers).
// ------------------------------------------------------------------
__global__ __launch_bounds__(1024) void fps_kernel(const float* __restrict__ xyz,
                                                   float* __restrict__ out_newxyz,
                                                   float* __restrict__ ws_newxyz) {
  const int b = blockIdx.x;
  const int t = threadIdx.x;
  __shared__ float sXYZ[NPTS * 3];
  __shared__ unsigned long long sRed[2][16];
  const float* xb = xyz + (size_t)b * 3 * NPTS;
  for (int i = t; i < NPTS; i += 1024) {
    sXYZ[i * 3 + 0] = xb[i];
    sXYZ[i * 3 + 1] = xb[NPTS + i];
    sXYZ[i * 3 + 2] = xb[2 * NPTS + i];
  }
  float px[4], py[4], pz[4], dist[4];
  {
    float4 x4 = ((const float4*)(xb))[t];
    float4 y4 = ((const float4*)(xb + NPTS))[t];
    float4 z4 = ((const float4*)(xb + 2 * NPTS))[t];
    px[0] = x4.x; px[1] = x4.y; px[2] = x4.z; px[3] = x4.w;
    py[0] = y4.x; py[1] = y4.y; py[2] = y4.z; py[3] = y4.w;
    pz[0] = z4.x; pz[1] = z4.y; pz[2] = z4.z; pz[3] = z4.w;
  }
#pragma unroll
  for (int j = 0; j < 4; ++j) dist[j] = 1e10f;
  __syncthreads();
  int f = 0;
  const int wave = t >> 6;
  const int lane = t & 63;
  for (int s = 0; s < NS; ++s) {
    float cx = sXYZ[f * 3 + 0], cy = sXYZ[f * 3 + 1], cz = sXYZ[f * 3 + 2];
    if (t == 0) {
      // output 0: new_xyz transposed (B,3,S)
      out_newxyz[b * 3 * NS + s] = cx;
      out_newxyz[b * 3 * NS + NS + s] = cy;
      out_newxyz[b * 3 * NS + 2 * NS + s] = cz;
      ws_newxyz[((b << 10) + s) * 3 + 0] = cx;
      ws_newxyz[((b << 10) + s) * 3 + 1] = cy;
      ws_newxyz[((b << 10) + s) * 3 + 2] = cz;
    }
    unsigned long long best = 0ull;
#pragma unroll
    for (int j = 0; j < 4; ++j) {
      // replicate jnp: sum((xyz - c)**2, -1) = ((dx*dx + dy*dy) + dz*dz), no fma
      float dx = __fadd_rn(px[j], -cx);
      float dy = __fadd_rn(py[j], -cy);
      float dz = __fadd_rn(pz[j], -cz);
      float d = __fadd_rn(__fadd_rn(__fmul_rn(dx, dx), __fmul_rn(dy, dy)), __fmul_rn(dz, dz));
      dist[j] = fminf(dist[j], d);
      unsigned long long key = ((unsigned long long)__float_as_uint(dist[j]) << 32) |
                               (unsigned long long)(0xFFFFFFFFu - (unsigned)(t * 4 + j));
      if (key > best) best = key;
    }
#pragma unroll
    for (int off = 1; off <= 32; off <<= 1) {
      unsigned long long oth = __shfl_xor(best, off, 64);
      if (oth > best) best = oth;
    }
    if (lane == 0) sRed[s & 1][wave] = best;
    __syncthreads();
    unsigned long long tot = sRed[s & 1][0];
#pragma unroll
    for (int w2 = 1; w2 < 16; ++w2) {
      unsigned long long oth = sRed[s & 1][w2];
      if (oth > tot) tot = oth;
    }
    f = (int)(0xFFFFFFFFu - (unsigned)(tot & 0xFFFFFFFFull));
  }
}

// ------------------------------------------------------------------
// Ball query: one wave per (b,s); first 32 indices (ascending) with
// d <= r^2, numpy-rounding-exact distance; pad with slot 0.
// ------------------------------------------------------------------
__global__ __launch_bounds__(256) void query_kernel(const float* __restrict__ xyz,
                                                    const float* __restrict__ ws_newxyz,
                                                    int* __restrict__ idx_ws) {
  const int w = threadIdx.x >> 6;
  const int lane = threadIdx.x & 63;
  const int p = blockIdx.x * 4 + w;  // 8192 pairs
  const int b = p >> 10;
  __shared__ int sIdx[4][32];
  const float* xb = xyz + (size_t)b * 3 * NPTS;
  const float cx = ws_newxyz[p * 3 + 0];
  const float cy = ws_newxyz[p * 3 + 1];
  const float cz = ws_newxyz[p * 3 + 2];
  const float ss = __fadd_rn(__fadd_rn(__fmul_rn(cx, cx), __fmul_rn(cy, cy)), __fmul_rn(cz, cz));
  const float r2 = (float)(0.4 * 0.4);
  int cnt = 0;
  for (int ci = 0; ci < 64 && cnt < 32; ++ci) {
    int n = ci * 64 + lane;
    float x = xb[n], y = xb[NPTS + n], z = xb[2 * NPTS + n];
    // d = (-2*dot + |src|^2) + |dst|^2, each op rounded, matching np order
    float dot = __fadd_rn(__fadd_rn(__fmul_rn(cx, x), __fmul_rn(cy, y)), __fmul_rn(cz, z));
    float dd = __fadd_rn(__fadd_rn(__fmul_rn(x, x), __fmul_rn(y, y)), __fmul_rn(z, z));
    float d = __fmul_rn(-2.0f, dot);
    d = __fadd_rn(d, ss);
    d = __fadd_rn(d, dd);
    d = fmaxf(d, 1e-12f);  // clip
    bool inc = (d <= r2);
    unsigned long long m = __ballot(inc);
    int slot = cnt + (int)__popcll(m & ((1ull << lane) - 1ull));
    if (inc && slot < 32) sIdx[w][slot] = n;
    cnt += (int)__popcll(m);
  }
  if (lane < 32) {
    int v;
    if (lane < cnt) v = sIdx[w][lane];
    else v = (cnt > 0) ? sIdx[w][0] : 0;
    idx_ws[p * 32 + lane] = v;
  }
}

// ------------------------------------------------------------------
// Conv (1x1 over grouped points) + bias + BN-stat partials.
// MODE 0: stage x by gathering xyz/points via idx (layer 0)
// MODE 1: stage x = relu(bn(yprev)) (layer 1/2 input), write y
// MODE 2: like 1 but epilogue max/min-pools over k instead of writing y
// Register-blocked 4x4 (o,k) per thread; W transposed in LDS.
// ------------------------------------------------------------------
template <int CIN, int COUT, int SPB, int MODE>
__global__ __launch_bounds__(256) void conv_kernel(
    const float* __restrict__ xin, const float* __restrict__ points,
    const int* __restrict__ idx_ws, const float* __restrict__ cen_ws,
    const float* __restrict__ W, const float* __restrict__ bias,
    const float* __restrict__ meanA, const float* __restrict__ rstdA,
    const float* __restrict__ gA, const float* __restrict__ btA,
    float* __restrict__ yout, float* __restrict__ pmax, float* __restrict__ pmin,
    float* __restrict__ partials) {
  constexpr int WP = COUT + 4;            // padded pitch, keeps 16B alignment
  constexpr int TPS = (COUT / 4) * 8;     // threads per s
  __shared__ __align__(16) float sW[CIN * WP];
  __shared__ __align__(16) float sX[SPB * CIN * 32];
  __shared__ int sIdx[SPB * 32];
  __shared__ float sCen[SPB * 4];
  __shared__ float sSum[COUT];
  __shared__ float sSq[COUT];
  __shared__ float sMax[8 * COUT];
  __shared__ float sMin[8 * COUT];

  const int t = threadIdx.x;
  const int pair0 = blockIdx.x * SPB;

  for (int f = t; f < CIN * COUT; f += 256) {
    int o = f / CIN;
    int c = f - o * CIN;
    sW[c * WP + o] = W[f];
  }
  if (t < COUT) { sSum[t] = 0.f; sSq[t] = 0.f; }

  if (MODE == 0) {
    for (int i = t; i < SPB * 32; i += 256) sIdx[i] = idx_ws[pair0 * 32 + i];
    for (int i = t; i < SPB * 3; i += 256) sCen[(i / 3) * 4 + (i % 3)] = cen_ws[pair0 * 3 + i];
    __syncthreads();
    for (int f = t; f < SPB * CIN * 32; f += 256) {
      int sl = f / (CIN * 32);
      int r = f - sl * (CIN * 32);
      int c = r >> 5;
      int k = r & 31;
      int p = pair0 + sl;
      int bb = p >> 10;
      int n = sIdx[sl * 32 + k];
      float v;
      if (c < 3) v = xin[bb * 3 * NPTS + c * NPTS + n] - sCen[sl * 4 + c];
      else       v = points[(size_t)bb * ND * NPTS + (c - 3) * NPTS + n];
      sX[f] = v;
    }
  } else {
    for (int f = t; f < SPB * CIN * 32; f += 256) {
      int c = (f >> 5) % CIN;  // CIN==64 here, folds to &63
      float v = xin[(size_t)pair0 * CIN * 32 + f];
      v = ((v - meanA[c]) * rstdA[c]) * gA[c] + btA[c];
      sX[f] = fmaxf(v, 0.f);
    }
  }
  __syncthreads();

  const int sl = t / TPS;
  const int tl = t - sl * TPS;
  const int k0 = (tl & 7) * 4;
  const int o0 = (tl >> 3) * 4;

  float acc[4][4];
#pragma unroll
  for (int i = 0; i < 4; ++i)
#pragma unroll
    for (int j = 0; j < 4; ++j) acc[i][j] = 0.f;

  const float* xrow = sX + sl * (CIN * 32);
#pragma unroll 4
  for (int c = 0; c < CIN; ++c) {
    float4 xv = *(const float4*)(xrow + c * 32 + k0);
    float4 wv = *(const float4*)(sW + c * WP + o0);
    float xa[4] = {xv.x, xv.y, xv.z, xv.w};
    float wa[4] = {wv.x, wv.y, wv.z, wv.w};
#pragma unroll
    for (int i = 0; i < 4; ++i)
#pragma unroll
      for (int j = 0; j < 4; ++j) acc[i][j] += wa[i] * xa[j];
  }
#pragma unroll
  for (int i = 0; i < 4; ++i) {
    float bo = bias[o0 + i];
#pragma unroll
    for (int j = 0; j < 4; ++j) acc[i][j] += bo;
  }
#pragma unroll
  for (int i = 0; i < 4; ++i) {
    float s1 = (acc[i][0] + acc[i][1]) + (acc[i][2] + acc[i][3]);
    float s2 = (acc[i][0] * acc[i][0] + acc[i][1] * acc[i][1]) +
               (acc[i][2] * acc[i][2] + acc[i][3] * acc[i][3]);
    atomicAdd(&sSum[o0 + i], s1);
    atomicAdd(&sSq[o0 + i], s2);
  }
  if (MODE < 2) {
#pragma unroll
    for (int i = 0; i < 4; ++i) {
      float4 v = make_float4(acc[i][0], acc[i][1], acc[i][2], acc[i][3]);
      *(float4*)(yout + (size_t)(pair0 + sl) * COUT * 32 + (o0 + i) * 32 + k0) = v;
    }
  } else {
#pragma unroll
    for (int i = 0; i < 4; ++i) {
      float mx = fmaxf(fmaxf(acc[i][0], acc[i][1]), fmaxf(acc[i][2], acc[i][3]));
      float mn = fminf(fminf(acc[i][0], acc[i][1]), fminf(acc[i][2], acc[i][3]));
      sMax[(k0 >> 2) * COUT + o0 + i] = mx;
      sMin[(k0 >> 2) * COUT + o0 + i] = mn;
    }
  }
  __syncthreads();
  if (t < COUT) {
    partials[(size_t)blockIdx.x * (COUT * 2) + t] = sSum[t];
    partials[(size_t)blockIdx.x * (COUT * 2) + COUT + t] = sSq[t];
    if (MODE == 2) {
      float mx = sMax[t];
      float mn = sMin[t];
#pragma unroll
      for (int q = 1; q < 8; ++q) {
        mx = fmaxf(mx, sMax[q * COUT + t]);
        mn = fminf(mn, sMin[q * COUT + t]);
      }
      pmax[pair0 * COUT + t] = mx;
      pmin[pair0 * COUT + t] = mn;
    }
  }
}

// one block per channel: f64 reduce of per-block partials -> mean, rstd
template <int COUT>
__global__ __launch_bounds__(256) void stats_kernel(const float* __restrict__ partials,
                                                    int nblocks,
                                                    float* __restrict__ meanA,
                                                    float* __restrict__ rstdA) {
  const int o = blockIdx.x;
  const int t = threadIdx.x;
  double s1 = 0.0, s2 = 0.0;
  for (int blk = t; blk < nblocks; blk += 256) {
    s1 += (double)partials[(size_t)blk * (COUT * 2) + o];
    s2 += (double)partials[(size_t)blk * (COUT * 2) + COUT + o];
  }
  __shared__ double r1[256], r2[256];
  r1[t] = s1; r2[t] = s2;
  __syncthreads();
  for (int st = 128; st > 0; st >>= 1) {
    if (t < st) { r1[t] += r1[t + st]; r2[t] += r2[t + st]; }
    __syncthreads();
  }
  if (t == 0) {
    const double Nr = 262144.0;  // B*K*S
    double mean = r1[0] / Nr;
    double var = r2[0] / Nr - mean * mean;
    meanA[o] = (float)mean;
    rstdA[o] = (float)(1.0 / sqrt(var + 1e-5));
  }
}

// normalize pooled value (max if slope>=0 else min; relu∘affine monotone)
__global__ __launch_bounds__(256) void final_kernel(const float* __restrict__ pmax,
                                                    const float* __restrict__ pmin,
                                                    const float* __restrict__ meanA,
                                                    const float* __restrict__ rstdA,
                                                    const float* __restrict__ gA,
                                                    const float* __restrict__ btA,
                                                    float* __restrict__ out) {
  int tid = blockIdx.x * 256 + threadIdx.x;  // 1048576 = 8*128*1024
  int b = tid >> 17;
  int c = (tid >> 10) & 127;
  int s = tid & 1023;
  int p = (b << 10) + s;
  float rs = rstdA[c], mn = meanA[c], gg = gA[c], bb = btA[c];
  float slope = rs * gg;
  float v = (slope >= 0.f) ? pmax[(size_t)p * 128 + c] : pmin[(size_t)p * 128 + c];
  float t1 = (v - mn) * rs;
  float t2 = t1 * gg + bb;
  out[tid] = fmaxf(t2, 0.f);
}

extern "C" void kernel_launch(void* const* d_in, const int* in_sizes, int n_in,
                              void* d_out, int out_size, void* d_ws, size_t ws_size,
                              hipStream_t stream) {
  (void)in_sizes; (void)n_in; (void)out_size; (void)ws_size;
  const float* xyz = (const float*)d_in[0];
  const float* points = (const float*)d_in[1];
  const float* W0 = (const float*)d_in[2];
  const float* b0 = (const float*)d_in[3];
  const float* g0 = (const float*)d_in[4];
  const float* bt0 = (const float*)d_in[5];
  const float* W1 = (const float*)d_in[6];
  const float* b1 = (const float*)d_in[7];
  const float* g1 = (const float*)d_in[8];
  const float* bt1 = (const float*)d_in[9];
  const float* W2 = (const float*)d_in[10];
  const float* b2 = (const float*)d_in[11];
  const float* g2 = (const float*)d_in[12];
  const float* bt2 = (const float*)d_in[13];
  float* out = (float*)d_out;

  float* ws = (float*)d_ws;
  size_t off = 0;
  float* newxyz = ws + off;  off += (size_t)NB * NS * 3;        // 24576
  int* idx = (int*)(ws + off); off += (size_t)NB * NS * NK;     // 262144
  float* y0 = ws + off;      off += (size_t)NB * NS * 64 * 32;  // 16.8M floats
  float* y1 = ws + off;      off += (size_t)NB * NS * 64 * 32;
  float* partials = ws + off; off += (size_t)8192 * 256;
  float* meanA = ws + off;   off += 128;
  float* rstdA = ws + off;   off += 128;
  float* pmaxb = ws + off;   off += (size_t)NB * NS * 128;
  float* pminb = ws + off;   off += (size_t)NB * NS * 128;

  fps_kernel<<<NB, 1024, 0, stream>>>(xyz, out, newxyz);
  query_kernel<<<2048, 256, 0, stream>>>(xyz, newxyz, idx);
  conv_kernel<67, 64, 2, 0><<<4096, 256, 0, stream>>>(
      xyz, points, idx, newxyz, W0, b0, nullptr, nullptr, nullptr, nullptr,
      y0, nullptr, nullptr, partials);
  stats_kernel<64><<<64, 256, 0, stream>>>(partials, 4096, meanA, rstdA);
  conv_kernel<64, 64, 2, 1><<<4096, 256, 0, stream>>>(
      y0, nullptr, nullptr, nullptr, W1, b1, meanA, rstdA, g0, bt0,
      y1, nullptr, nullptr, partials);
  stats_kernel<64><<<64, 256, 0, stream>>>(partials, 4096, meanA, rstdA);
  conv_kernel<64, 128, 1, 2><<<8192, 256, 0, stream>>>(
      y1, nullptr, nullptr, nullptr, W2, b2, meanA, rstdA, g1, bt1,
      nullptr, pmaxb, pminb, partials);
  stats_kernel<128><<<128, 256, 0, stream>>>(partials, 8192, meanA, rstdA);
  final_kernel<<<4096, 256, 0, stream>>>(pmaxb, pminb, meanA, rstdA, g2, bt2,
                                         out + NB * NS * 3);
}

// Round 2
// 1569.629 us; speedup vs baseline: 1.0973x; 1.0973x over previous
//
#include <hip/hip_runtime.h>
#include <cstddef>
#include <cstdint>

#define NB 8
#define NPTS 4096
#define NS 1024
#define NK 32
#define ND 64

// ------------------------------------------------------------------
// FPS: one block per batch, 1024 threads, 4 points/thread in registers.
// Argmax carries the winning point's xyz through the reduction, so no
// index lookup is ever needed. Wave level: 6-step DPP int-max on dist
// (VALU pipe, no ds_swizzle), ballot picks smallest lane (= smallest
// global index -> jnp.argmax first-occurrence). Cross-wave: one
// ds_read_b128 per wave + 4-step DPP keep-earliest tree in rows of 16.
// One barrier per iteration, parity-double-buffered LDS.
// ------------------------------------------------------------------
#define DPP_IMAX(v, ctrl)                                                     \
  {                                                                           \
    int _o = __builtin_amdgcn_update_dpp(v, v, ctrl, 0xf, 0xf, false);        \
    v = (_o > v) ? _o : v;                                                    \
  }

__global__ __launch_bounds__(1024) void fps_kernel(const float* __restrict__ xyz,
                                                   float* __restrict__ out_newxyz,
                                                   float* __restrict__ ws_newxyz) {
  const int b = blockIdx.x;
  const int t = threadIdx.x;
  const int wave = t >> 6;
  const int lane = t & 63;
  __shared__ float4 sRed[2][16];
  const float* xb = xyz + (size_t)b * 3 * NPTS;

  float px[4], py[4], pz[4], dist[4];
  {
    float4 x4 = ((const float4*)(xb))[t];
    float4 y4 = ((const float4*)(xb + NPTS))[t];
    float4 z4 = ((const float4*)(xb + 2 * NPTS))[t];
    px[0] = x4.x; px[1] = x4.y; px[2] = x4.z; px[3] = x4.w;
    py[0] = y4.x; py[1] = y4.y; py[2] = y4.z; py[3] = y4.w;
    pz[0] = z4.x; pz[1] = z4.y; pz[2] = z4.z; pz[3] = z4.w;
  }
#pragma unroll
  for (int j = 0; j < 4; ++j) dist[j] = 1e10f;

  // first centroid = point 0 (farthest init = 0)
  float cx = xb[0], cy = xb[NPTS], cz = xb[2 * NPTS];

  for (int s = 0; s < NS; ++s) {
    if (t == 0) {
      out_newxyz[b * 3 * NS + s] = cx;
      out_newxyz[b * 3 * NS + NS + s] = cy;
      out_newxyz[b * 3 * NS + 2 * NS + s] = cz;
      ws_newxyz[((b << 10) + s) * 3 + 0] = cx;
      ws_newxyz[((b << 10) + s) * 3 + 1] = cy;
      ws_newxyz[((b << 10) + s) * 3 + 2] = cz;
    }
    // update dists (bit-exact np order) + local first-occurrence argmax
    float bd = -1.0f, bx = 0.f, by = 0.f, bz = 0.f;
#pragma unroll
    for (int j = 0; j < 4; ++j) {
      float dx = __fadd_rn(px[j], -cx);
      float dy = __fadd_rn(py[j], -cy);
      float dz = __fadd_rn(pz[j], -cz);
      float d = __fadd_rn(__fadd_rn(__fmul_rn(dx, dx), __fmul_rn(dy, dy)), __fmul_rn(dz, dz));
      dist[j] = fminf(dist[j], d);
      if (dist[j] > bd) { bd = dist[j]; bx = px[j]; by = py[j]; bz = pz[j]; }
    }
    // wave-level max of bd (nonneg floats: int compare == float order)
    int v = __float_as_int(bd);
    DPP_IMAX(v, 0x111)  // row_shr:1
    DPP_IMAX(v, 0x112)  // row_shr:2
    DPP_IMAX(v, 0x114)  // row_shr:4
    DPP_IMAX(v, 0x118)  // row_shr:8
    DPP_IMAX(v, 0x142)  // row_bcast:15
    DPP_IMAX(v, 0x143)  // row_bcast:31
    float wavemax = __int_as_float(__builtin_amdgcn_readlane(v, 63));
    unsigned long long m = __ballot(bd == wavemax);
    int first = __ffsll(m) - 1;
    if (lane == first) sRed[s & 1][wave] = make_float4(wavemax, bx, by, bz);
    __syncthreads();
    // cross-wave: every row of 16 holds a full copy; keep-earliest tree
    float4 c = sRed[s & 1][lane & 15];
#pragma unroll
    for (int stp = 0; stp < 4; ++stp) {
      const int ctrl = 0x110 | (1 << stp);  // row_shr 1,2,4,8
      int nd, nx, ny, nz;
      switch (stp) {
        case 0:
          nd = __builtin_amdgcn_update_dpp(__float_as_int(c.x), __float_as_int(c.x), 0x111, 0xf, 0xf, false);
          nx = __builtin_amdgcn_update_dpp(__float_as_int(c.y), __float_as_int(c.y), 0x111, 0xf, 0xf, false);
          ny = __builtin_amdgcn_update_dpp(__float_as_int(c.z), __float_as_int(c.z), 0x111, 0xf, 0xf, false);
          nz = __builtin_amdgcn_update_dpp(__float_as_int(c.w), __float_as_int(c.w), 0x111, 0xf, 0xf, false);
          break;
        case 1:
          nd = __builtin_amdgcn_update_dpp(__float_as_int(c.x), __float_as_int(c.x), 0x112, 0xf, 0xf, false);
          nx = __builtin_amdgcn_update_dpp(__float_as_int(c.y), __float_as_int(c.y), 0x112, 0xf, 0xf, false);
          ny = __builtin_amdgcn_update_dpp(__float_as_int(c.z), __float_as_int(c.z), 0x112, 0xf, 0xf, false);
          nz = __builtin_amdgcn_update_dpp(__float_as_int(c.w), __float_as_int(c.w), 0x112, 0xf, 0xf, false);
          break;
        case 2:
          nd = __builtin_amdgcn_update_dpp(__float_as_int(c.x), __float_as_int(c.x), 0x114, 0xf, 0xf, false);
          nx = __builtin_amdgcn_update_dpp(__float_as_int(c.y), __float_as_int(c.y), 0x114, 0xf, 0xf, false);
          ny = __builtin_amdgcn_update_dpp(__float_as_int(c.z), __float_as_int(c.z), 0x114, 0xf, 0xf, false);
          nz = __builtin_amdgcn_update_dpp(__float_as_int(c.w), __float_as_int(c.w), 0x114, 0xf, 0xf, false);
          break;
        default:
          nd = __builtin_amdgcn_update_dpp(__float_as_int(c.x), __float_as_int(c.x), 0x118, 0xf, 0xf, false);
          nx = __builtin_amdgcn_update_dpp(__float_as_int(c.y), __float_as_int(c.y), 0x118, 0xf, 0xf, false);
          ny = __builtin_amdgcn_update_dpp(__float_as_int(c.z), __float_as_int(c.z), 0x118, 0xf, 0xf, false);
          nz = __builtin_amdgcn_update_dpp(__float_as_int(c.w), __float_as_int(c.w), 0x118, 0xf, 0xf, false);
          break;
      }
      (void)ctrl;
      // shifted value comes from a LOWER lane (earlier wave) -> >= keeps
      // the earlier wave on ties (first-occurrence; wave idx ranges disjoint)
      if (__int_as_float(nd) >= c.x) {
        c.x = __int_as_float(nd);
        c.y = __int_as_float(nx);
        c.z = __int_as_float(ny);
        c.w = __int_as_float(nz);
      }
    }
    cx = __int_as_float(__builtin_amdgcn_readlane(__float_as_int(c.y), 15));
    cy = __int_as_float(__builtin_amdgcn_readlane(__float_as_int(c.z), 15));
    cz = __int_as_float(__builtin_amdgcn_readlane(__float_as_int(c.w), 15));
  }
}

// ------------------------------------------------------------------
// Ball query: one wave per (b,s); first 32 indices (ascending) with
// d <= r^2, numpy-rounding-exact distance; pad with slot 0.
// ------------------------------------------------------------------
__global__ __launch_bounds__(256) void query_kernel(const float* __restrict__ xyz,
                                                    const float* __restrict__ ws_newxyz,
                                                    int* __restrict__ idx_ws) {
  const int w = threadIdx.x >> 6;
  const int lane = threadIdx.x & 63;
  const int p = blockIdx.x * 4 + w;  // 8192 pairs
  const int b = p >> 10;
  __shared__ int sIdx[4][32];
  const float* xb = xyz + (size_t)b * 3 * NPTS;
  const float cx = ws_newxyz[p * 3 + 0];
  const float cy = ws_newxyz[p * 3 + 1];
  const float cz = ws_newxyz[p * 3 + 2];
  const float ss = __fadd_rn(__fadd_rn(__fmul_rn(cx, cx), __fmul_rn(cy, cy)), __fmul_rn(cz, cz));
  const float r2 = (float)(0.4 * 0.4);
  int cnt = 0;
  for (int ci = 0; ci < 64 && cnt < 32; ++ci) {
    int n = ci * 64 + lane;
    float x = xb[n], y = xb[NPTS + n], z = xb[2 * NPTS + n];
    // d = (-2*dot + |src|^2) + |dst|^2, each op rounded, matching np order
    float dot = __fadd_rn(__fadd_rn(__fmul_rn(cx, x), __fmul_rn(cy, y)), __fmul_rn(cz, z));
    float dd = __fadd_rn(__fadd_rn(__fmul_rn(x, x), __fmul_rn(y, y)), __fmul_rn(z, z));
    float d = __fmul_rn(-2.0f, dot);
    d = __fadd_rn(d, ss);
    d = __fadd_rn(d, dd);
    d = fmaxf(d, 1e-12f);  // clip
    bool inc = (d <= r2);
    unsigned long long m = __ballot(inc);
    int slot = cnt + (int)__popcll(m & ((1ull << lane) - 1ull));
    if (inc && slot < 32) sIdx[w][slot] = n;
    cnt += (int)__popcll(m);
  }
  if (lane < 32) {
    int v;
    if (lane < cnt) v = sIdx[w][lane];
    else v = (cnt > 0) ? sIdx[w][0] : 0;
    idx_ws[p * 32 + lane] = v;
  }
}

// ------------------------------------------------------------------
// Conv (1x1 over grouped points) + bias + BN-stat partials.
// MODE 0: stage x by gathering xyz/points via idx (layer 0)
// MODE 1: stage x = relu(bn(yprev)) (layer 1/2 input), write y
// MODE 2: like 1 but epilogue max/min-pools over k instead of writing y
// Register-blocked 4x4 (o,k) per thread; W transposed in LDS.
// ------------------------------------------------------------------
template <int CIN, int COUT, int SPB, int MODE>
__global__ __launch_bounds__(256) void conv_kernel(
    const float* __restrict__ xin, const float* __restrict__ points,
    const int* __restrict__ idx_ws, const float* __restrict__ cen_ws,
    const float* __restrict__ W, const float* __restrict__ bias,
    const float* __restrict__ meanA, const float* __restrict__ rstdA,
    const float* __restrict__ gA, const float* __restrict__ btA,
    float* __restrict__ yout, float* __restrict__ pmax, float* __restrict__ pmin,
    float* __restrict__ partials) {
  constexpr int WP = COUT + 4;            // padded pitch, keeps 16B alignment
  constexpr int TPS = (COUT / 4) * 8;     // threads per s
  __shared__ __align__(16) float sW[CIN * WP];
  __shared__ __align__(16) float sX[SPB * CIN * 32];
  __shared__ int sIdx[SPB * 32];
  __shared__ float sCen[SPB * 4];
  __shared__ float sSum[COUT];
  __shared__ float sSq[COUT];
  __shared__ float sMax[8 * COUT];
  __shared__ float sMin[8 * COUT];

  const int t = threadIdx.x;
  const int pair0 = blockIdx.x * SPB;

  for (int f = t; f < CIN * COUT; f += 256) {
    int o = f / CIN;
    int c = f - o * CIN;
    sW[c * WP + o] = W[f];
  }
  if (t < COUT) { sSum[t] = 0.f; sSq[t] = 0.f; }

  if (MODE == 0) {
    for (int i = t; i < SPB * 32; i += 256) sIdx[i] = idx_ws[pair0 * 32 + i];
    for (int i = t; i < SPB * 3; i += 256) sCen[(i / 3) * 4 + (i % 3)] = cen_ws[pair0 * 3 + i];
    __syncthreads();
    for (int f = t; f < SPB * CIN * 32; f += 256) {
      int sl = f / (CIN * 32);
      int r = f - sl * (CIN * 32);
      int c = r >> 5;
      int k = r & 31;
      int p = pair0 + sl;
      int bb = p >> 10;
      int n = sIdx[sl * 32 + k];
      float v;
      if (c < 3) v = xin[bb * 3 * NPTS + c * NPTS + n] - sCen[sl * 4 + c];
      else       v = points[(size_t)bb * ND * NPTS + (c - 3) * NPTS + n];
      sX[f] = v;
    }
  } else {
    for (int f = t; f < SPB * CIN * 32; f += 256) {
      int c = (f >> 5) % CIN;  // CIN==64 here, folds to &63
      float v = xin[(size_t)pair0 * CIN * 32 + f];
      v = ((v - meanA[c]) * rstdA[c]) * gA[c] + btA[c];
      sX[f] = fmaxf(v, 0.f);
    }
  }
  __syncthreads();

  const int sl = t / TPS;
  const int tl = t - sl * TPS;
  const int k0 = (tl & 7) * 4;
  const int o0 = (tl >> 3) * 4;

  float acc[4][4];
#pragma unroll
  for (int i = 0; i < 4; ++i)
#pragma unroll
    for (int j = 0; j < 4; ++j) acc[i][j] = 0.f;

  const float* xrow = sX + sl * (CIN * 32);
#pragma unroll 4
  for (int c = 0; c < CIN; ++c) {
    float4 xv = *(const float4*)(xrow + c * 32 + k0);
    float4 wv = *(const float4*)(sW + c * WP + o0);
    float xa[4] = {xv.x, xv.y, xv.z, xv.w};
    float wa[4] = {wv.x, wv.y, wv.z, wv.w};
#pragma unroll
    for (int i = 0; i < 4; ++i)
#pragma unroll
      for (int j = 0; j < 4; ++j) acc[i][j] += wa[i] * xa[j];
  }
#pragma unroll
  for (int i = 0; i < 4; ++i) {
    float bo = bias[o0 + i];
#pragma unroll
    for (int j = 0; j < 4; ++j) acc[i][j] += bo;
  }
#pragma unroll
  for (int i = 0; i < 4; ++i) {
    float s1 = (acc[i][0] + acc[i][1]) + (acc[i][2] + acc[i][3]);
    float s2 = (acc[i][0] * acc[i][0] + acc[i][1] * acc[i][1]) +
               (acc[i][2] * acc[i][2] + acc[i][3] * acc[i][3]);
    atomicAdd(&sSum[o0 + i], s1);
    atomicAdd(&sSq[o0 + i], s2);
  }
  if (MODE < 2) {
#pragma unroll
    for (int i = 0; i < 4; ++i) {
      float4 v = make_float4(acc[i][0], acc[i][1], acc[i][2], acc[i][3]);
      *(float4*)(yout + (size_t)(pair0 + sl) * COUT * 32 + (o0 + i) * 32 + k0) = v;
    }
  } else {
#pragma unroll
    for (int i = 0; i < 4; ++i) {
      float mx = fmaxf(fmaxf(acc[i][0], acc[i][1]), fmaxf(acc[i][2], acc[i][3]));
      float mn = fminf(fminf(acc[i][0], acc[i][1]), fminf(acc[i][2], acc[i][3]));
      sMax[(k0 >> 2) * COUT + o0 + i] = mx;
      sMin[(k0 >> 2) * COUT + o0 + i] = mn;
    }
  }
  __syncthreads();
  if (t < COUT) {
    partials[(size_t)blockIdx.x * (COUT * 2) + t] = sSum[t];
    partials[(size_t)blockIdx.x * (COUT * 2) + COUT + t] = sSq[t];
    if (MODE == 2) {
      float mx = sMax[t];
      float mn = sMin[t];
#pragma unroll
      for (int q = 1; q < 8; ++q) {
        mx = fmaxf(mx, sMax[q * COUT + t]);
        mn = fminf(mn, sMin[q * COUT + t]);
      }
      pmax[pair0 * COUT + t] = mx;
      pmin[pair0 * COUT + t] = mn;
    }
  }
}

// one block per channel: f64 reduce of per-block partials -> mean, rstd
template <int COUT>
__global__ __launch_bounds__(256) void stats_kernel(const float* __restrict__ partials,
                                                    int nblocks,
                                                    float* __restrict__ meanA,
                                                    float* __restrict__ rstdA) {
  const int o = blockIdx.x;
  const int t = threadIdx.x;
  double s1 = 0.0, s2 = 0.0;
  for (int blk = t; blk < nblocks; blk += 256) {
    s1 += (double)partials[(size_t)blk * (COUT * 2) + o];
    s2 += (double)partials[(size_t)blk * (COUT * 2) + COUT + o];
  }
  __shared__ double r1[256], r2[256];
  r1[t] = s1; r2[t] = s2;
  __syncthreads();
  for (int st = 128; st > 0; st >>= 1) {
    if (t < st) { r1[t] += r1[t + st]; r2[t] += r2[t + st]; }
    __syncthreads();
  }
  if (t == 0) {
    const double Nr = 262144.0;  // B*K*S
    double mean = r1[0] / Nr;
    double var = r2[0] / Nr - mean * mean;
    meanA[o] = (float)mean;
    rstdA[o] = (float)(1.0 / sqrt(var + 1e-5));
  }
}

// normalize pooled value (max if slope>=0 else min; relu∘affine monotone)
__global__ __launch_bounds__(256) void final_kernel(const float* __restrict__ pmax,
                                                    const float* __restrict__ pmin,
                                                    const float* __restrict__ meanA,
                                                    const float* __restrict__ rstdA,
                                                    const float* __restrict__ gA,
                                                    const float* __restrict__ btA,
                                                    float* __restrict__ out) {
  int tid = blockIdx.x * 256 + threadIdx.x;  // 1048576 = 8*128*1024
  int b = tid >> 17;
  int c = (tid >> 10) & 127;
  int s = tid & 1023;
  int p = (b << 10) + s;
  float rs = rstdA[c], mn = meanA[c], gg = gA[c], bb = btA[c];
  float slope = rs * gg;
  float v = (slope >= 0.f) ? pmax[(size_t)p * 128 + c] : pmin[(size_t)p * 128 + c];
  float t1 = (v - mn) * rs;
  float t2 = t1 * gg + bb;
  out[tid] = fmaxf(t2, 0.f);
}

extern "C" void kernel_launch(void* const* d_in, const int* in_sizes, int n_in,
                              void* d_out, int out_size, void* d_ws, size_t ws_size,
                              hipStream_t stream) {
  (void)in_sizes; (void)n_in; (void)out_size; (void)ws_size;
  const float* xyz = (const float*)d_in[0];
  const float* points = (const float*)d_in[1];
  const float* W0 = (const float*)d_in[2];
  const float* b0 = (const float*)d_in[3];
  const float* g0 = (const float*)d_in[4];
  const float* bt0 = (const float*)d_in[5];
  const float* W1 = (const float*)d_in[6];
  const float* b1 = (const float*)d_in[7];
  const float* g1 = (const float*)d_in[8];
  const float* bt1 = (const float*)d_in[9];
  const float* W2 = (const float*)d_in[10];
  const float* b2 = (const float*)d_in[11];
  const float* g2 = (const float*)d_in[12];
  const float* bt2 = (const float*)d_in[13];
  float* out = (float*)d_out;

  float* ws = (float*)d_ws;
  size_t off = 0;
  float* newxyz = ws + off;  off += (size_t)NB * NS * 3;        // 24576
  int* idx = (int*)(ws + off); off += (size_t)NB * NS * NK;     // 262144
  float* y0 = ws + off;      off += (size_t)NB * NS * 64 * 32;  // 16.8M floats
  float* y1 = ws + off;      off += (size_t)NB * NS * 64 * 32;
  float* partials = ws + off; off += (size_t)8192 * 256;
  float* meanA = ws + off;   off += 128;
  float* rstdA = ws + off;   off += 128;
  float* pmaxb = ws + off;   off += (size_t)NB * NS * 128;
  float* pminb = ws + off;   off += (size_t)NB * NS * 128;

  fps_kernel<<<NB, 1024, 0, stream>>>(xyz, out, newxyz);
  query_kernel<<<2048, 256, 0, stream>>>(xyz, newxyz, idx);
  conv_kernel<67, 64, 2, 0><<<4096, 256, 0, stream>>>(
      xyz, points, idx, newxyz, W0, b0, nullptr, nullptr, nullptr, nullptr,
      y0, nullptr, nullptr, partials);
  stats_kernel<64><<<64, 256, 0, stream>>>(partials, 4096, meanA, rstdA);
  conv_kernel<64, 64, 2, 1><<<4096, 256, 0, stream>>>(
      y0, nullptr, nullptr, nullptr, W1, b1, meanA, rstdA, g0, bt0,
      y1, nullptr, nullptr, partials);
  stats_kernel<64><<<64, 256, 0, stream>>>(partials, 4096, meanA, rstdA);
  conv_kernel<64, 128, 1, 2><<<8192, 256, 0, stream>>>(
      y1, nullptr, nullptr, nullptr, W2, b2, meanA, rstdA, g1, bt1,
      nullptr, pmaxb, pminb, partials);
  stats_kernel<128><<<128, 256, 0, stream>>>(partials, 8192, meanA, rstdA);
  final_kernel<<<4096, 256, 0, stream>>>(pmaxb, pminb, meanA, rstdA, g2, bt2,
                                         out + NB * NS * 3);
}

// Round 4
// 1240.482 us; speedup vs baseline: 1.3884x; 1.2653x over previous
//
#include <hip/hip_runtime.h>
#include <cstddef>
#include <cstdint>

#define NB 8
#define NPTS 4096
#define NS 1024
#define NK 32
#define ND 64

// ------------------------------------------------------------------
// FPS: one block per batch, 512 threads x 8 points in registers.
// VALU-minimal reduction: wave DPP max on dist only; ballot picks the
// first lane; that lane alone packs (dist<<32 | ~idx) into LDS. Cross-
// wave: ds_read_b64 of 8 keys + 3-step u64 DPP scan. Centroid xyz via
// LDS broadcast lookup; outputs dumped once at the end.
// Distance arithmetic is bit-exact vs numpy (no fma, same op order);
// fmin over finite f32 is order-free so lazy order is irrelevant.
// ------------------------------------------------------------------
#define DPP_IMAX(v, ctrl)                                                     \
  {                                                                           \
    int _o = __builtin_amdgcn_update_dpp(v, v, ctrl, 0xf, 0xf, false);        \
    v = (_o > v) ? _o : v;                                                    \
  }

// u64 (hi,lo) keep-max scan step; ctrl must be a literal constant.
#define DPP_U64MAX(hi, lo, ctrl)                                              \
  {                                                                           \
    unsigned _nh = (unsigned)__builtin_amdgcn_update_dpp((int)(hi), (int)(hi),\
                                                         ctrl, 0xf, 0xf, false);\
    unsigned _nl = (unsigned)__builtin_amdgcn_update_dpp((int)(lo), (int)(lo),\
                                                         ctrl, 0xf, 0xf, false);\
    bool _gt = (_nh > (hi)) || (_nh == (hi) && _nl > (lo));                   \
    hi = _gt ? _nh : (hi);                                                    \
    lo = _gt ? _nl : (lo);                                                    \
  }

__global__ __launch_bounds__(512) void fps_kernel(const float* __restrict__ xyz,
                                                  float* __restrict__ out_newxyz,
                                                  float* __restrict__ ws_newxyz) {
  const int b = blockIdx.x;
  const int t = threadIdx.x;   // 0..511
  const int wave = t >> 6;     // 0..7
  const int lane = t & 63;
  __shared__ float sXYZ[NPTS * 3];              // 48 KB, point-major
  __shared__ unsigned long long sRed[2][8];
  __shared__ int sWidx[NS];
  const float* xb = xyz + (size_t)b * 3 * NPTS;

  // stage xyz point-major (write stride 3 floats -> conflict-free)
  for (int i = t; i < NPTS; i += 512) {
    sXYZ[i * 3 + 0] = xb[i];
    sXYZ[i * 3 + 1] = xb[NPTS + i];
    sXYZ[i * 3 + 2] = xb[2 * NPTS + i];
  }
  if (t == 0) sWidx[0] = 0;

  float px[8], py[8], pz[8], dist[8];
  {
    float4 a0 = ((const float4*)xb)[2 * t];
    float4 a1 = ((const float4*)xb)[2 * t + 1];
    float4 b0 = ((const float4*)(xb + NPTS))[2 * t];
    float4 b1 = ((const float4*)(xb + NPTS))[2 * t + 1];
    float4 c0 = ((const float4*)(xb + 2 * NPTS))[2 * t];
    float4 c1 = ((const float4*)(xb + 2 * NPTS))[2 * t + 1];
    px[0] = a0.x; px[1] = a0.y; px[2] = a0.z; px[3] = a0.w;
    px[4] = a1.x; px[5] = a1.y; px[6] = a1.z; px[7] = a1.w;
    py[0] = b0.x; py[1] = b0.y; py[2] = b0.z; py[3] = b0.w;
    py[4] = b1.x; py[5] = b1.y; py[6] = b1.z; py[7] = b1.w;
    pz[0] = c0.x; pz[1] = c0.y; pz[2] = c0.z; pz[3] = c0.w;
    pz[4] = c1.x; pz[5] = c1.y; pz[6] = c1.z; pz[7] = c1.w;
  }
#pragma unroll
  for (int j = 0; j < 8; ++j) dist[j] = 1e10f;

  float cx = xb[0], cy = xb[NPTS], cz = xb[2 * NPTS];  // centroid 0

  for (int s = 0; s < NS; ++s) {
    // bit-exact dist update
#pragma unroll
    for (int j = 0; j < 8; ++j) {
      float dx = __fadd_rn(px[j], -cx);
      float dy = __fadd_rn(py[j], -cy);
      float dz = __fadd_rn(pz[j], -cz);
      float d = __fadd_rn(__fadd_rn(__fmul_rn(dx, dx), __fmul_rn(dy, dy)), __fmul_rn(dz, dz));
      dist[j] = fminf(dist[j], d);
    }
    float m = fmaxf(fmaxf(fmaxf(dist[0], dist[1]), fmaxf(dist[2], dist[3])),
                    fmaxf(fmaxf(dist[4], dist[5]), fmaxf(dist[6], dist[7])));
    // wave max (nonneg floats: int order == float order)
    int v = __float_as_int(m);
    DPP_IMAX(v, 0x111)
    DPP_IMAX(v, 0x112)
    DPP_IMAX(v, 0x114)
    DPP_IMAX(v, 0x118)
    DPP_IMAX(v, 0x142)
    DPP_IMAX(v, 0x143)
    const int wm_i = __builtin_amdgcn_readlane(v, 63);
    const float wm = __int_as_float(wm_i);
    unsigned long long claim = __ballot(m == wm);
    int firstlane = __ffsll(claim) - 1;
    if (lane == firstlane) {
      int j = 7;
#pragma unroll
      for (int jj = 6; jj >= 0; --jj)
        if (dist[jj] == wm) j = jj;  // smallest matching j
      unsigned widx = (unsigned)(t * 8 + j);
      sRed[s & 1][wave] = ((unsigned long long)(unsigned)wm_i << 32) |
                          (unsigned long long)(0xFFFFFFFFu - widx);
    }
    __syncthreads();
    // cross-wave: 8 keys, inclusive u64 max scan -> lane 7
    unsigned long long k = sRed[s & 1][lane & 7];
    unsigned hi = (unsigned)(k >> 32), lo = (unsigned)k;
    DPP_U64MAX(hi, lo, 0x111)
    DPP_U64MAX(hi, lo, 0x112)
    DPP_U64MAX(hi, lo, 0x114)
    const unsigned gl = (unsigned)__builtin_amdgcn_readlane((int)lo, 7);
    const int widx = (int)(0xFFFFFFFFu - gl);
    cx = sXYZ[widx * 3 + 0];
    cy = sXYZ[widx * 3 + 1];
    cz = sXYZ[widx * 3 + 2];
    if (t == 0 && s < NS - 1) sWidx[s + 1] = widx;
  }
  __syncthreads();
  // dump centroids: out (B,3,S) and ws (b*S+s)*3
  for (int s2 = t; s2 < NS; s2 += 512) {
    int w = sWidx[s2];
    float x = sXYZ[w * 3 + 0], y = sXYZ[w * 3 + 1], z = sXYZ[w * 3 + 2];
    out_newxyz[b * 3 * NS + s2] = x;
    out_newxyz[b * 3 * NS + NS + s2] = y;
    out_newxyz[b * 3 * NS + 2 * NS + s2] = z;
    ws_newxyz[((b << 10) + s2) * 3 + 0] = x;
    ws_newxyz[((b << 10) + s2) * 3 + 1] = y;
    ws_newxyz[((b << 10) + s2) * 3 + 2] = z;
  }
}

// ------------------------------------------------------------------
// Ball query: one wave per (b,s); first 32 indices (ascending) with
// d <= r^2, numpy-rounding-exact distance; pad with slot 0.
// ------------------------------------------------------------------
__global__ __launch_bounds__(256) void query_kernel(const float* __restrict__ xyz,
                                                    const float* __restrict__ ws_newxyz,
                                                    int* __restrict__ idx_ws) {
  const int w = threadIdx.x >> 6;
  const int lane = threadIdx.x & 63;
  const int p = blockIdx.x * 4 + w;  // 8192 pairs
  const int b = p >> 10;
  __shared__ int sIdx[4][32];
  const float* xb = xyz + (size_t)b * 3 * NPTS;
  const float cx = ws_newxyz[p * 3 + 0];
  const float cy = ws_newxyz[p * 3 + 1];
  const float cz = ws_newxyz[p * 3 + 2];
  const float ss = __fadd_rn(__fadd_rn(__fmul_rn(cx, cx), __fmul_rn(cy, cy)), __fmul_rn(cz, cz));
  const float r2 = (float)(0.4 * 0.4);
  int cnt = 0;
  for (int ci = 0; ci < 64 && cnt < 32; ++ci) {
    int n = ci * 64 + lane;
    float x = xb[n], y = xb[NPTS + n], z = xb[2 * NPTS + n];
    float dot = __fadd_rn(__fadd_rn(__fmul_rn(cx, x), __fmul_rn(cy, y)), __fmul_rn(cz, z));
    float dd = __fadd_rn(__fadd_rn(__fmul_rn(x, x), __fmul_rn(y, y)), __fmul_rn(z, z));
    float d = __fmul_rn(-2.0f, dot);
    d = __fadd_rn(d, ss);
    d = __fadd_rn(d, dd);
    d = fmaxf(d, 1e-12f);  // clip
    bool inc = (d <= r2);
    unsigned long long m = __ballot(inc);
    int slot = cnt + (int)__popcll(m & ((1ull << lane) - 1ull));
    if (inc && slot < 32) sIdx[w][slot] = n;
    cnt += (int)__popcll(m);
  }
  if (lane < 32) {
    int v;
    if (lane < cnt) v = sIdx[w][lane];
    else v = (cnt > 0) ? sIdx[w][0] : 0;
    idx_ws[p * 32 + lane] = v;
  }
}

// ------------------------------------------------------------------
// Conv (1x1 over grouped points) + bias + BN-stat partials.
// MODE 0: stage x by gathering xyz/points via idx (layer 0)
// MODE 1: stage x = relu(bn(yprev)) (layer 1/2 input), write y
// MODE 2: like 1 but epilogue max/min-pools over k instead of writing y
// ------------------------------------------------------------------
template <int CIN, int COUT, int SPB, int MODE>
__global__ __launch_bounds__(256) void conv_kernel(
    const float* __restrict__ xin, const float* __restrict__ points,
    const int* __restrict__ idx_ws, const float* __restrict__ cen_ws,
    const float* __restrict__ W, const float* __restrict__ bias,
    const float* __restrict__ meanA, const float* __restrict__ rstdA,
    const float* __restrict__ gA, const float* __restrict__ btA,
    float* __restrict__ yout, float* __restrict__ pmax, float* __restrict__ pmin,
    float* __restrict__ partials) {
  constexpr int WP = COUT + 4;
  constexpr int TPS = (COUT / 4) * 8;
  __shared__ __align__(16) float sW[CIN * WP];
  __shared__ __align__(16) float sX[SPB * CIN * 32];
  __shared__ int sIdx[SPB * 32];
  __shared__ float sCen[SPB * 4];
  __shared__ float sSum[COUT];
  __shared__ float sSq[COUT];
  __shared__ float sMax[8 * COUT];
  __shared__ float sMin[8 * COUT];

  const int t = threadIdx.x;
  const int pair0 = blockIdx.x * SPB;

  for (int f = t; f < CIN * COUT; f += 256) {
    int o = f / CIN;
    int c = f - o * CIN;
    sW[c * WP + o] = W[f];
  }
  if (t < COUT) { sSum[t] = 0.f; sSq[t] = 0.f; }

  if (MODE == 0) {
    for (int i = t; i < SPB * 32; i += 256) sIdx[i] = idx_ws[pair0 * 32 + i];
    for (int i = t; i < SPB * 3; i += 256) sCen[(i / 3) * 4 + (i % 3)] = cen_ws[pair0 * 3 + i];
    __syncthreads();
    for (int f = t; f < SPB * CIN * 32; f += 256) {
      int sl = f / (CIN * 32);
      int r = f - sl * (CIN * 32);
      int c = r >> 5;
      int k = r & 31;
      int p = pair0 + sl;
      int bb = p >> 10;
      int n = sIdx[sl * 32 + k];
      float v;
      if (c < 3) v = xin[bb * 3 * NPTS + c * NPTS + n] - sCen[sl * 4 + c];
      else       v = points[(size_t)bb * ND * NPTS + (c - 3) * NPTS + n];
      sX[f] = v;
    }
  } else {
    for (int f = t; f < SPB * CIN * 32; f += 256) {
      int c = (f >> 5) % CIN;
      float v = xin[(size_t)pair0 * CIN * 32 + f];
      v = ((v - meanA[c]) * rstdA[c]) * gA[c] + btA[c];
      sX[f] = fmaxf(v, 0.f);
    }
  }
  __syncthreads();

  const int sl = t / TPS;
  const int tl = t - sl * TPS;
  const int k0 = (tl & 7) * 4;
  const int o0 = (tl >> 3) * 4;

  float acc[4][4];
#pragma unroll
  for (int i = 0; i < 4; ++i)
#pragma unroll
    for (int j = 0; j < 4; ++j) acc[i][j] = 0.f;

  const float* xrow = sX + sl * (CIN * 32);
#pragma unroll 4
  for (int c = 0; c < CIN; ++c) {
    float4 xv = *(const float4*)(xrow + c * 32 + k0);
    float4 wv = *(const float4*)(sW + c * WP + o0);
    float xa[4] = {xv.x, xv.y, xv.z, xv.w};
    float wa[4] = {wv.x, wv.y, wv.z, wv.w};
#pragma unroll
    for (int i = 0; i < 4; ++i)
#pragma unroll
      for (int j = 0; j < 4; ++j) acc[i][j] += wa[i] * xa[j];
  }
#pragma unroll
  for (int i = 0; i < 4; ++i) {
    float bo = bias[o0 + i];
#pragma unroll
    for (int j = 0; j < 4; ++j) acc[i][j] += bo;
  }
#pragma unroll
  for (int i = 0; i < 4; ++i) {
    float s1 = (acc[i][0] + acc[i][1]) + (acc[i][2] + acc[i][3]);
    float s2 = (acc[i][0] * acc[i][0] + acc[i][1] * acc[i][1]) +
               (acc[i][2] * acc[i][2] + acc[i][3] * acc[i][3]);
    atomicAdd(&sSum[o0 + i], s1);
    atomicAdd(&sSq[o0 + i], s2);
  }
  if (MODE < 2) {
#pragma unroll
    for (int i = 0; i < 4; ++i) {
      float4 v = make_float4(acc[i][0], acc[i][1], acc[i][2], acc[i][3]);
      *(float4*)(yout + (size_t)(pair0 + sl) * COUT * 32 + (o0 + i) * 32 + k0) = v;
    }
  } else {
#pragma unroll
    for (int i = 0; i < 4; ++i) {
      float mx = fmaxf(fmaxf(acc[i][0], acc[i][1]), fmaxf(acc[i][2], acc[i][3]));
      float mn = fminf(fminf(acc[i][0], acc[i][1]), fminf(acc[i][2], acc[i][3]));
      sMax[(k0 >> 2) * COUT + o0 + i] = mx;
      sMin[(k0 >> 2) * COUT + o0 + i] = mn;
    }
  }
  __syncthreads();
  if (t < COUT) {
    partials[(size_t)blockIdx.x * (COUT * 2) + t] = sSum[t];
    partials[(size_t)blockIdx.x * (COUT * 2) + COUT + t] = sSq[t];
    if (MODE == 2) {
      float mx = sMax[t];
      float mn = sMin[t];
#pragma unroll
      for (int q = 1; q < 8; ++q) {
        mx = fmaxf(mx, sMax[q * COUT + t]);
        mn = fminf(mn, sMin[q * COUT + t]);
      }
      pmax[pair0 * COUT + t] = mx;
      pmin[pair0 * COUT + t] = mn;
    }
  }
}

// one block per channel: f64 reduce of per-block partials -> mean, rstd
template <int COUT>
__global__ __launch_bounds__(256) void stats_kernel(const float* __restrict__ partials,
                                                    int nblocks,
                                                    float* __restrict__ meanA,
                                                    float* __restrict__ rstdA) {
  const int o = blockIdx.x;
  const int t = threadIdx.x;
  double s1 = 0.0, s2 = 0.0;
  for (int blk = t; blk < nblocks; blk += 256) {
    s1 += (double)partials[(size_t)blk * (COUT * 2) + o];
    s2 += (double)partials[(size_t)blk * (COUT * 2) + COUT + o];
  }
  __shared__ double r1[256], r2[256];
  r1[t] = s1; r2[t] = s2;
  __syncthreads();
  for (int st = 128; st > 0; st >>= 1) {
    if (t < st) { r1[t] += r1[t + st]; r2[t] += r2[t + st]; }
    __syncthreads();
  }
  if (t == 0) {
    const double Nr = 262144.0;  // B*K*S
    double mean = r1[0] / Nr;
    double var = r2[0] / Nr - mean * mean;
    meanA[o] = (float)mean;
    rstdA[o] = (float)(1.0 / sqrt(var + 1e-5));
  }
}

// normalize pooled value (max if slope>=0 else min; relu∘affine monotone)
__global__ __launch_bounds__(256) void final_kernel(const float* __restrict__ pmax,
                                                    const float* __restrict__ pmin,
                                                    const float* __restrict__ meanA,
                                                    const float* __restrict__ rstdA,
                                                    const float* __restrict__ gA,
                                                    const float* __restrict__ btA,
                                                    float* __restrict__ out) {
  int tid = blockIdx.x * 256 + threadIdx.x;  // 1048576 = 8*128*1024
  int b = tid >> 17;
  int c = (tid >> 10) & 127;
  int s = tid & 1023;
  int p = (b << 10) + s;
  float rs = rstdA[c], mn = meanA[c], gg = gA[c], bb = btA[c];
  float slope = rs * gg;
  float v = (slope >= 0.f) ? pmax[(size_t)p * 128 + c] : pmin[(size_t)p * 128 + c];
  float t1 = (v - mn) * rs;
  float t2 = t1 * gg + bb;
  out[tid] = fmaxf(t2, 0.f);
}

extern "C" void kernel_launch(void* const* d_in, const int* in_sizes, int n_in,
                              void* d_out, int out_size, void* d_ws, size_t ws_size,
                              hipStream_t stream) {
  (void)in_sizes; (void)n_in; (void)out_size; (void)ws_size;
  const float* xyz = (const float*)d_in[0];
  const float* points = (const float*)d_in[1];
  const float* W0 = (const float*)d_in[2];
  const float* b0 = (const float*)d_in[3];
  const float* g0 = (const float*)d_in[4];
  const float* bt0 = (const float*)d_in[5];
  const float* W1 = (const float*)d_in[6];
  const float* b1 = (const float*)d_in[7];
  const float* g1 = (const float*)d_in[8];
  const float* bt1 = (const float*)d_in[9];
  const float* W2 = (const float*)d_in[10];
  const float* b2 = (const float*)d_in[11];
  const float* g2 = (const float*)d_in[12];
  const float* bt2 = (const float*)d_in[13];
  float* out = (float*)d_out;

  float* ws = (float*)d_ws;
  size_t off = 0;
  float* newxyz = ws + off;  off += (size_t)NB * NS * 3;
  int* idx = (int*)(ws + off); off += (size_t)NB * NS * NK;
  float* y0 = ws + off;      off += (size_t)NB * NS * 64 * 32;
  float* y1 = ws + off;      off += (size_t)NB * NS * 64 * 32;
  float* partials = ws + off; off += (size_t)8192 * 256;
  float* meanA = ws + off;   off += 128;
  float* rstdA = ws + off;   off += 128;
  float* pmaxb = ws + off;   off += (size_t)NB * NS * 128;
  float* pminb = ws + off;   off += (size_t)NB * NS * 128;

  fps_kernel<<<NB, 512, 0, stream>>>(xyz, out, newxyz);
  query_kernel<<<2048, 256, 0, stream>>>(xyz, newxyz, idx);
  conv_kernel<67, 64, 2, 0><<<4096, 256, 0, stream>>>(
      xyz, points, idx, newxyz, W0, b0, nullptr, nullptr, nullptr, nullptr,
      y0, nullptr, nullptr, partials);
  stats_kernel<64><<<64, 256, 0, stream>>>(partials, 4096, meanA, rstdA);
  conv_kernel<64, 64, 2, 1><<<4096, 256, 0, stream>>>(
      y0, nullptr, nullptr, nullptr, W1, b1, meanA, rstdA, g0, bt0,
      y1, nullptr, nullptr, partials);
  stats_kernel<64><<<64, 256, 0, stream>>>(partials, 4096, meanA, rstdA);
  conv_kernel<64, 128, 1, 2><<<8192, 256, 0, stream>>>(
      y1, nullptr, nullptr, nullptr, W2, b2, meanA, rstdA, g1, bt1,
      nullptr, pmaxb, pminb, partials);
  stats_kernel<128><<<128, 256, 0, stream>>>(partials, 8192, meanA, rstdA);
  final_kernel<<<4096, 256, 0, stream>>>(pmaxb, pminb, meanA, rstdA, g2, bt2,
                                         out + NB * NS * 3);
}